// Round 2
// baseline (743.322 us; speedup 1.0000x reference)
//
#include <hip/hip_runtime.h>
#include <cstddef>

constexpr int kB = 8, kC = 256, kCI = 128, kN = 4096, kM = 1024;
constexpr float kEPS = 1e-5f;

// ---------------------------------------------------------------------------
// 2x2 avg pool: in fp32 [B*C][64][64] -> out fp32 [B*C][1024]
// ---------------------------------------------------------------------------
__global__ __launch_bounds__(256) void pool_kernel(const float* __restrict__ in,
                                                   float* __restrict__ out) {
    int idx = blockIdx.x * 256 + threadIdx.x;      // B*C*1024 total
    int m  = idx & (kM - 1);
    int bc = idx >> 10;
    int mh = m >> 5, mw = m & 31;
    const float* p = in + ((size_t)bc * 64 + 2 * mh) * 64 + 2 * mw;
    float2 a = *(const float2*)p;          // 2 consecutive
    float2 b = *(const float2*)(p + 64);   // next row
    out[idx] = 0.25f * (a.x + a.y + b.x + b.y);
}

// ---------------------------------------------------------------------------
// conv1x1: out[b,ci,px-range] = sum_c W[ci,c] * x[b,c,px] + bias[ci]
// x: [B, C, Mn] fp32, W: fp32 [CI, C], bias fp32 [CI]
// LAYOUT 0: out[(b*Mn + n)*CI + ci]   (n-major, ci contiguous)
// LAYOUT 1: out[(b*CI + ci)*Mn + n]   (ci-major, n contiguous)
// block: 256 thr, tile 64 px x 128 ci, K-chunks of 64
// ---------------------------------------------------------------------------
template <int LAYOUT>
__global__ __launch_bounds__(256) void conv1x1_kernel(const float* __restrict__ x,
                                                      const float* __restrict__ w,
                                                      const float* __restrict__ bias,
                                                      float* __restrict__ out, int Mn) {
    __shared__ float x_lds[64 * 64];        // [c][px]
    __shared__ float w_lds[kCI * 65];       // [ci][c], stride 65 (pad)
    int t  = threadIdx.x;
    int b  = blockIdx.y;
    int n0 = blockIdx.x * 64;
    int pxg = t & 15;          // px group -> px = pxg*4 + i
    int cig = t >> 4;          // 0..15 -> ci0 = cig*8
    int ci0 = cig * 8;

    float acc[8][4];
#pragma unroll
    for (int j = 0; j < 8; j++)
#pragma unroll
        for (int i = 0; i < 4; i++) acc[j][i] = 0.0f;

    for (int c0 = 0; c0 < kC; c0 += 64) {
        __syncthreads();
        // stage x chunk [64 c][64 px]
#pragma unroll
        for (int s = 0; s < 16; s++) {
            int idx = t + 256 * s;
            int px = idx & 63, c = idx >> 6;
            x_lds[c * 64 + px] = x[(size_t)(b * kC + c0 + c) * Mn + n0 + px];
        }
        // stage w chunk [128 ci][64 c] (stride 65)
#pragma unroll
        for (int s = 0; s < 32; s++) {
            int idx = t + 256 * s;
            int c = idx & 63, ci = idx >> 6;
            w_lds[ci * 65 + c] = w[ci * kC + c0 + c];
        }
        __syncthreads();
#pragma unroll 4
        for (int c = 0; c < 64; c++) {
            float4 a = *(const float4*)&x_lds[c * 64 + pxg * 4];
#pragma unroll
            for (int j = 0; j < 8; j++) {
                float wv = w_lds[(ci0 + j) * 65 + c];
                acc[j][0] += wv * a.x;
                acc[j][1] += wv * a.y;
                acc[j][2] += wv * a.z;
                acc[j][3] += wv * a.w;
            }
        }
    }

    float bs[8];
#pragma unroll
    for (int j = 0; j < 8; j++) bs[j] = bias[ci0 + j];

    if (LAYOUT == 0) {
        float* op = out + (size_t)(b * Mn + n0 + pxg * 4) * kCI + ci0;
#pragma unroll
        for (int pxi = 0; pxi < 4; pxi++) {
            float4 v0, v1;
            v0.x = acc[0][pxi] + bs[0]; v0.y = acc[1][pxi] + bs[1];
            v0.z = acc[2][pxi] + bs[2]; v0.w = acc[3][pxi] + bs[3];
            v1.x = acc[4][pxi] + bs[4]; v1.y = acc[5][pxi] + bs[5];
            v1.z = acc[6][pxi] + bs[6]; v1.w = acc[7][pxi] + bs[7];
            *(float4*)(op + (size_t)pxi * kCI)     = v0;
            *(float4*)(op + (size_t)pxi * kCI + 4) = v1;
        }
    } else {
        float* op = out + (size_t)(b * kCI + ci0) * Mn + n0 + pxg * 4;
#pragma unroll
        for (int j = 0; j < 8; j++) {
            float4 v0;
            v0.x = acc[j][0] + bs[j]; v0.y = acc[j][1] + bs[j];
            v0.z = acc[j][2] + bs[j]; v0.w = acc[j][3] + bs[j];
            *(float4*)(op + (size_t)j * Mn) = v0;
        }
    }
}

// ---------------------------------------------------------------------------
// attention: per block handles (b, 8 rows of N).
//  f[r][m] = sum_ci theta[n0+r][ci] * phi[ci][m]   (m = 0..1023)
//  p = softmax_m(f);  y[r][ci] = sum_m p[m] * g[m][ci]
// theta: [B,N,CI] fp32; phi: [B,CI,M] fp32; g: [B,M,CI] fp32; y: [B,N,CI] fp32
// ---------------------------------------------------------------------------
__global__ __launch_bounds__(256) void attn_kernel(const float* __restrict__ theta,
                                                   const float* __restrict__ phi,
                                                   const float* __restrict__ g,
                                                   float* __restrict__ y) {
    __shared__ float th_lds[8 * kCI];     // 4 KB
    __shared__ float f_lds[8 * kM];       // 32 KB
    int t  = threadIdx.x;
    int b  = blockIdx.y;
    int n0 = blockIdx.x * 8;

    // stage theta rows
    {
        int r = t >> 5, ci4 = (t & 31) * 4;
        *(float4*)&th_lds[r * kCI + ci4] =
            *(const float4*)&theta[(size_t)(b * kN + n0 + r) * kCI + ci4];
    }
    __syncthreads();

    // ---- stage f: thread t handles m in {t, t+256, t+512, t+768}, all 8 rows
    float acc[8][4];
#pragma unroll
    for (int r = 0; r < 8; r++)
#pragma unroll
        for (int k = 0; k < 4; k++) acc[r][k] = 0.0f;

    const float* phiB = phi + (size_t)b * kCI * kM;
    for (int ci = 0; ci < kCI; ci += 4) {
        float ph[4][4];
#pragma unroll
        for (int i = 0; i < 4; i++)
#pragma unroll
            for (int k = 0; k < 4; k++)
                ph[i][k] = phiB[(size_t)(ci + i) * kM + t + 256 * k];
#pragma unroll
        for (int r = 0; r < 8; r++) {
            float4 th = *(const float4*)&th_lds[r * kCI + ci];
#pragma unroll
            for (int k = 0; k < 4; k++)
                acc[r][k] += th.x * ph[0][k] + th.y * ph[1][k] +
                             th.z * ph[2][k] + th.w * ph[3][k];
        }
    }
#pragma unroll
    for (int r = 0; r < 8; r++)
#pragma unroll
        for (int k = 0; k < 4; k++) f_lds[r * kM + t + 256 * k] = acc[r][k];
    __syncthreads();

    // ---- softmax: wave w handles rows w and w+4
    int wv = t >> 6, lane = t & 63;
#pragma unroll
    for (int rr = 0; rr < 2; rr++) {
        int r = wv + rr * 4;
        float vals[16];
        float mx = -1e30f;
#pragma unroll
        for (int j = 0; j < 16; j++) {
            vals[j] = f_lds[r * kM + lane + 64 * j];
            mx = fmaxf(mx, vals[j]);
        }
#pragma unroll
        for (int off = 32; off >= 1; off >>= 1) mx = fmaxf(mx, __shfl_xor(mx, off, 64));
        float s = 0.0f;
#pragma unroll
        for (int j = 0; j < 16; j++) {
            vals[j] = __expf(vals[j] - mx);
            s += vals[j];
        }
#pragma unroll
        for (int off = 32; off >= 1; off >>= 1) s += __shfl_xor(s, off, 64);
        float inv = 1.0f / s;
#pragma unroll
        for (int j = 0; j < 16; j++) f_lds[r * kM + lane + 64 * j] = vals[j] * inv;
    }
    __syncthreads();

    // ---- stage y: thread handles 2 ci (ci2, ci2+1), m-quarter q (uniform per wave)
    int ci2 = (t & 63) * 2;
    int q   = t >> 6;
    float ay[8][2];
#pragma unroll
    for (int r = 0; r < 8; r++) { ay[r][0] = 0.0f; ay[r][1] = 0.0f; }
    const float* gB = g + (size_t)b * kM * kCI;
    for (int m4 = q * 256; m4 < q * 256 + 256; m4 += 4) {
        float2 gv[4];
#pragma unroll
        for (int mm = 0; mm < 4; mm++)
            gv[mm] = *(const float2*)&gB[(size_t)(m4 + mm) * kCI + ci2];
#pragma unroll
        for (int r = 0; r < 8; r++) {
            float4 p = *(const float4*)&f_lds[r * kM + m4];
            ay[r][0] += p.x * gv[0].x + p.y * gv[1].x + p.z * gv[2].x + p.w * gv[3].x;
            ay[r][1] += p.x * gv[0].y + p.y * gv[1].y + p.z * gv[2].y + p.w * gv[3].y;
        }
    }
    __syncthreads();   // all f reads done; f_lds becomes scratch

    float* scr = f_lds;
    if (q & 1) {
#pragma unroll
        for (int r = 0; r < 8; r++) {
            float2 v2 = make_float2(ay[r][0], ay[r][1]);
            *(float2*)&scr[((q >> 1) * 8 + r) * kCI + ci2] = v2;
        }
    }
    __syncthreads();
    if (!(q & 1)) {
#pragma unroll
        for (int r = 0; r < 8; r++) {
            float2 o = *(const float2*)&scr[((q >> 1) * 8 + r) * kCI + ci2];
            ay[r][0] += o.x; ay[r][1] += o.y;
        }
    }
    __syncthreads();
    if (q == 2) {
#pragma unroll
        for (int r = 0; r < 8; r++) {
            float2 v2 = make_float2(ay[r][0], ay[r][1]);
            *(float2*)&scr[r * kCI + ci2] = v2;
        }
    }
    __syncthreads();
    if (q == 0) {
#pragma unroll
        for (int r = 0; r < 8; r++) {
            float2 o = *(const float2*)&scr[r * kCI + ci2];
            float2 v2 = make_float2(ay[r][0] + o.x, ay[r][1] + o.y);
            *(float2*)&y[(size_t)(b * kN + n0 + r) * kCI + ci2] = v2;
        }
    }
}

// ---------------------------------------------------------------------------
// transpose y [B][N][CI] -> yT [B][CI][N], 32x32 tiles
// ---------------------------------------------------------------------------
__global__ __launch_bounds__(256) void transpose_kernel(const float* __restrict__ in,
                                                        float* __restrict__ out) {
    __shared__ float tile[32][33];
    int b   = blockIdx.z;
    int n0  = blockIdx.x * 32;
    int ci0 = blockIdx.y * 32;
    int tx = threadIdx.x & 31, ty = threadIdx.x >> 5;   // ty 0..7
#pragma unroll
    for (int j = 0; j < 4; j++) {
        int row = ty + 8 * j;
        tile[row][tx] = in[(size_t)(b * kN + n0 + row) * kCI + ci0 + tx];
    }
    __syncthreads();
#pragma unroll
    for (int j = 0; j < 4; j++) {
        int row = ty + 8 * j;
        out[(size_t)(b * kCI + ci0 + row) * kN + n0 + tx] = tile[tx][row];
    }
}

// ---------------------------------------------------------------------------
// final: out[b,co,n] = (sum_ci Ww[co,ci]*yT[b,ci,n] + bw - mean)*scale + beta + v
//        scale = gamma * rsqrt(var+eps); out fp32
// tile: 64 px x 256 co (4 passes of 64 co)
// ---------------------------------------------------------------------------
__global__ __launch_bounds__(256) void final_kernel(const float* __restrict__ yT,
                                                    const float* __restrict__ Ww,
                                                    const float* __restrict__ bw,
                                                    const float* __restrict__ gamma,
                                                    const float* __restrict__ beta,
                                                    const float* __restrict__ mean,
                                                    const float* __restrict__ var,
                                                    const float* __restrict__ v,
                                                    float* __restrict__ out) {
    __shared__ float y_lds[kCI * 64];     // [ci][px], 32 KB
    __shared__ float w_lds[64 * 129];     // [co'][ci] stride 129, 33 KB
    int t  = threadIdx.x;
    int b  = blockIdx.y;
    int n0 = blockIdx.x * 64;
    int pxg = t & 15;      // px = pxg*4 + i
    int cog = t >> 4;      // co' = cog*4 + jj

    // stage y tile (coalesced float4, natural layout: no conflicts)
#pragma unroll
    for (int s = 0; s < 8; s++) {
        int idx = t + 256 * s;                 // 2048 float4 loads
        int p4 = (idx & 15) * 4, ci = idx >> 4;
        *(float4*)&y_lds[ci * 64 + p4] =
            *(const float4*)&yT[(size_t)(b * kCI + ci) * kN + n0 + p4];
    }

    for (int cpass = 0; cpass < 4; cpass++) {
        __syncthreads();
#pragma unroll
        for (int s = 0; s < 32; s++) {
            int idx = t + 256 * s;
            int ci = idx & 127, cop = idx >> 7;
            w_lds[cop * 129 + ci] = Ww[(cpass * 64 + cop) * kCI + ci];
        }
        __syncthreads();

        float acc[4][4];
#pragma unroll
        for (int jj = 0; jj < 4; jj++)
#pragma unroll
            for (int i = 0; i < 4; i++) acc[jj][i] = 0.0f;

#pragma unroll 4
        for (int ci = 0; ci < kCI; ci++) {
            float4 a = *(const float4*)&y_lds[ci * 64 + pxg * 4];
#pragma unroll
            for (int jj = 0; jj < 4; jj++) {
                float wv = w_lds[(cog * 4 + jj) * 129 + ci];
                acc[jj][0] += wv * a.x;
                acc[jj][1] += wv * a.y;
                acc[jj][2] += wv * a.z;
                acc[jj][3] += wv * a.w;
            }
        }

#pragma unroll
        for (int jj = 0; jj < 4; jj++) {
            int co = cpass * 64 + cog * 4 + jj;
            float sc = gamma[co] * rsqrtf(var[co] + kEPS);
            float bb = (bw[co] - mean[co]) * sc + beta[co];
            size_t base = (size_t)(b * kC + co) * kN + n0 + pxg * 4;
            float4 vv = *(const float4*)(v + base);
            float4 ov;
            ov.x = acc[jj][0] * sc + bb + vv.x;
            ov.y = acc[jj][1] * sc + bb + vv.y;
            ov.z = acc[jj][2] * sc + bb + vv.z;
            ov.w = acc[jj][3] * sc + bb + vv.w;
            *(float4*)(out + base) = ov;
        }
    }
}

// ---------------------------------------------------------------------------
extern "C" void kernel_launch(void* const* d_in, const int* in_sizes, int n_in,
                              void* d_out, int out_size, void* d_ws, size_t ws_size,
                              hipStream_t stream) {
    (void)in_sizes; (void)n_in; (void)out_size; (void)ws_size;
    const float* q     = (const float*)d_in[0];
    const float* k     = (const float*)d_in[1];
    const float* v     = (const float*)d_in[2];
    const float* Wg    = (const float*)d_in[3];
    const float* bg    = (const float*)d_in[4];
    const float* Wth   = (const float*)d_in[5];
    const float* bth   = (const float*)d_in[6];
    const float* Wph   = (const float*)d_in[7];
    const float* bph   = (const float*)d_in[8];
    const float* Ww    = (const float*)d_in[9];
    const float* bw    = (const float*)d_in[10];
    const float* gamma = (const float*)d_in[11];
    const float* beta  = (const float*)d_in[12];
    const float* mean  = (const float*)d_in[13];
    const float* var   = (const float*)d_in[14];
    float* out = (float*)d_out;

    float* ws = (float*)d_ws;
    // region reuse: [0,4M): qp+vp, later y.  [4M,8M): theta, later yT.
    float* qp    = ws;                 // 2,097,152
    float* vp    = ws + 2097152;       // 2,097,152
    float* yv    = ws;                 // 4,194,304 (after qp/vp consumed)
    float* theta = ws + 4194304;       // 4,194,304
    float* yT    = theta;              // (after theta consumed)
    float* phi   = ws + 8388608;       // 1,048,576
    float* g     = ws + 9437184;       // 1,048,576  -> total 10,485,760 fl = 40 MiB

    pool_kernel<<<dim3(8192), 256, 0, stream>>>(q, qp);
    pool_kernel<<<dim3(8192), 256, 0, stream>>>(v, vp);
    conv1x1_kernel<0><<<dim3(64, 8), 256, 0, stream>>>(k, Wth, bth, theta, kN);
    conv1x1_kernel<1><<<dim3(16, 8), 256, 0, stream>>>(qp, Wph, bph, phi, kM);
    conv1x1_kernel<0><<<dim3(16, 8), 256, 0, stream>>>(vp, Wg, bg, g, kM);
    attn_kernel<<<dim3(512, 8), 256, 0, stream>>>(theta, phi, g, yv);
    transpose_kernel<<<dim3(128, 4, 8), 256, 0, stream>>>(yv, yT);
    final_kernel<<<dim3(64, 8), 256, 0, stream>>>(yT, Ww, bw, gamma, beta, mean, var, v, out);
}

// Round 3
// 486.859 us; speedup vs baseline: 1.5268x; 1.5268x over previous
//
#include <hip/hip_runtime.h>
#include <cstddef>

typedef unsigned short u16;
typedef unsigned int u32;
typedef __attribute__((ext_vector_type(8))) __bf16 bf16x8;
typedef __attribute__((ext_vector_type(4))) float f32x4;

constexpr int kB = 8, kC = 256, kCI = 128, kN = 4096, kM = 1024;
constexpr float kEPS = 1e-5f;

__device__ __forceinline__ u16 f2bf(float f) {
    u32 u = __float_as_uint(f);
    u32 r = (u + 0x7fffu + ((u >> 16) & 1u)) >> 16;
    return (u16)r;
}

// ---------------------------------------------------------------------------
// 2x2 avg pool: in fp32 [B*C][64][64] -> out fp32 [B*C][1024]
// ---------------------------------------------------------------------------
__global__ __launch_bounds__(256) void pool_kernel(const float* __restrict__ in,
                                                   float* __restrict__ out) {
    int idx = blockIdx.x * 256 + threadIdx.x;
    int m  = idx & (kM - 1);
    int bc = idx >> 10;
    int mh = m >> 5, mw = m & 31;
    const float* p = in + ((size_t)bc * 64 + 2 * mh) * 64 + 2 * mw;
    float2 a = *(const float2*)p;
    float2 b = *(const float2*)(p + 64);
    out[idx] = 0.25f * (a.x + a.y + b.x + b.y);
}

// ---------------------------------------------------------------------------
// conv1x1 -> bf16 output.
// LAYOUT 0: out[(b*Mn + n)*CI + ci]   (n-major, ci contiguous)
// LAYOUT 1: out[(b*CI + ci)*Mn + n]   (ci-major, n contiguous)
// ---------------------------------------------------------------------------
template <int LAYOUT>
__global__ __launch_bounds__(256) void conv1x1_kernel(const float* __restrict__ x,
                                                      const float* __restrict__ w,
                                                      const float* __restrict__ bias,
                                                      u16* __restrict__ out, int Mn) {
    __shared__ float x_lds[64 * 64];        // [c][px]
    __shared__ float w_lds[kCI * 65];       // [ci][c], stride 65 (pad)
    int t  = threadIdx.x;
    int b  = blockIdx.y;
    int n0 = blockIdx.x * 64;
    int pxg = t & 15;
    int cig = t >> 4;
    int ci0 = cig * 8;

    float acc[8][4];
#pragma unroll
    for (int j = 0; j < 8; j++)
#pragma unroll
        for (int i = 0; i < 4; i++) acc[j][i] = 0.0f;

    for (int c0 = 0; c0 < kC; c0 += 64) {
        __syncthreads();
#pragma unroll
        for (int s = 0; s < 16; s++) {
            int idx = t + 256 * s;
            int px = idx & 63, c = idx >> 6;
            x_lds[c * 64 + px] = x[(size_t)(b * kC + c0 + c) * Mn + n0 + px];
        }
#pragma unroll
        for (int s = 0; s < 32; s++) {
            int idx = t + 256 * s;
            int c = idx & 63, ci = idx >> 6;
            w_lds[ci * 65 + c] = w[ci * kC + c0 + c];
        }
        __syncthreads();
#pragma unroll 4
        for (int c = 0; c < 64; c++) {
            float4 a = *(const float4*)&x_lds[c * 64 + pxg * 4];
#pragma unroll
            for (int j = 0; j < 8; j++) {
                float wv = w_lds[(ci0 + j) * 65 + c];
                acc[j][0] += wv * a.x;
                acc[j][1] += wv * a.y;
                acc[j][2] += wv * a.z;
                acc[j][3] += wv * a.w;
            }
        }
    }

    float bs[8];
#pragma unroll
    for (int j = 0; j < 8; j++) bs[j] = bias[ci0 + j];

    if (LAYOUT == 0) {
        u16* op = out + (size_t)(b * Mn + n0 + pxg * 4) * kCI + ci0;
#pragma unroll
        for (int pxi = 0; pxi < 4; pxi++) {
            uint4 pk;
            pk.x = (u32)f2bf(acc[0][pxi] + bs[0]) | ((u32)f2bf(acc[1][pxi] + bs[1]) << 16);
            pk.y = (u32)f2bf(acc[2][pxi] + bs[2]) | ((u32)f2bf(acc[3][pxi] + bs[3]) << 16);
            pk.z = (u32)f2bf(acc[4][pxi] + bs[4]) | ((u32)f2bf(acc[5][pxi] + bs[5]) << 16);
            pk.w = (u32)f2bf(acc[6][pxi] + bs[6]) | ((u32)f2bf(acc[7][pxi] + bs[7]) << 16);
            *(uint4*)(op + (size_t)pxi * kCI) = pk;
        }
    } else {
        u16* op = out + (size_t)(b * kCI + ci0) * Mn + n0 + pxg * 4;
#pragma unroll
        for (int j = 0; j < 8; j++) {
            uint2 pk;
            pk.x = (u32)f2bf(acc[j][0] + bs[j]) | ((u32)f2bf(acc[j][1] + bs[j]) << 16);
            pk.y = (u32)f2bf(acc[j][2] + bs[j]) | ((u32)f2bf(acc[j][3] + bs[j]) << 16);
            *(uint2*)(op + (size_t)j * Mn) = pk;
        }
    }
}

// ---------------------------------------------------------------------------
// Flash attention, bf16 MFMA.
// theta: bf16 [B][N][CI]; phi: bf16 [B][M][CI]; g: bf16 [B][CI][M]
// y: fp32 [B][N][CI]
// block = 256 thr = 4 waves; 64 N-rows per block (16 per wave); m-chunks of 64.
// 16x16x32 bf16 MFMA. C-layout: col=lane&15, row=quad*4+reg.
// A-layout: A[row=lane&15][k=quad*8+j]. B-layout: B[k=quad*8+j][col=lane&15].
// ---------------------------------------------------------------------------
__global__ __launch_bounds__(256) void attn_kernel(const u16* __restrict__ theta,
                                                   const u16* __restrict__ phi,
                                                   const u16* __restrict__ g,
                                                   float* __restrict__ y) {
    __shared__ __align__(16) u16 th_lds[64 * 136];    // [n][ci] pad->136
    __shared__ __align__(16) u16 ph_lds[64 * 136];    // [m][ci] pad->136
    __shared__ __align__(16) u16 g_lds[128 * 72];     // [ci][m] pad->72
    __shared__ __align__(16) u16 p_lds[4 * 16 * 72];  // per-wave [n][m] pad->72

    int t = threadIdx.x, b = blockIdx.y, n0 = blockIdx.x * 64;
    int w = t >> 6, lane = t & 63, l15 = lane & 15, quad = lane >> 4;

    // stage theta tile 64x128
    const u16* thg = theta + (size_t)(b * kN + n0) * kCI;
#pragma unroll
    for (int it = 0; it < 4; it++) {
        int idx = t + 256 * it;
        int row = idx >> 4, col = (idx & 15) * 8;
        *(uint4*)&th_lds[row * 136 + col] = *(const uint4*)&thg[(size_t)row * kCI + col];
    }

    f32x4 oacc[8];
#pragma unroll
    for (int i = 0; i < 8; i++) oacc[i] = (f32x4){0.f, 0.f, 0.f, 0.f};
    float mprev[4], lsum[4];
#pragma unroll
    for (int r = 0; r < 4; r++) { mprev[r] = -1e30f; lsum[r] = 0.f; }

    const u16* phB = phi + (size_t)b * kM * kCI;
    const u16* gB  = g   + (size_t)b * kCI * kM;

    for (int c0 = 0; c0 < kM; c0 += 64) {
        __syncthreads();
        // stage phi chunk [64 m][128 ci]
#pragma unroll
        for (int it = 0; it < 4; it++) {
            int idx = t + 256 * it;
            int row = idx >> 4, col = (idx & 15) * 8;
            *(uint4*)&ph_lds[row * 136 + col] =
                *(const uint4*)&phB[(size_t)(c0 + row) * kCI + col];
        }
        // stage g chunk [128 ci][64 m]
#pragma unroll
        for (int it = 0; it < 4; it++) {
            int idx = t + 256 * it;
            int row = idx >> 3, col = (idx & 7) * 8;
            *(uint4*)&g_lds[row * 72 + col] =
                *(const uint4*)&gB[(size_t)row * kM + c0 + col];
        }
        __syncthreads();

        // S = theta_tile(16x128) . phi_chunk^T -> 4 m-tiles of 16x16
        f32x4 sacc[4];
#pragma unroll
        for (int mt = 0; mt < 4; mt++) sacc[mt] = (f32x4){0.f, 0.f, 0.f, 0.f};
#pragma unroll
        for (int kk = 0; kk < 4; kk++) {
            bf16x8 a = *(const bf16x8*)&th_lds[(w * 16 + l15) * 136 + kk * 32 + quad * 8];
#pragma unroll
            for (int mt = 0; mt < 4; mt++) {
                bf16x8 bb = *(const bf16x8*)&ph_lds[(mt * 16 + l15) * 136 + kk * 32 + quad * 8];
                sacc[mt] = __builtin_amdgcn_mfma_f32_16x16x32_bf16(a, bb, sacc[mt], 0, 0, 0);
            }
        }

        // online softmax (row = quad*4 + r; 16 cols per tile across l15)
#pragma unroll
        for (int r = 0; r < 4; r++) {
            float mc = fmaxf(fmaxf(sacc[0][r], sacc[1][r]), fmaxf(sacc[2][r], sacc[3][r]));
            mc = fmaxf(mc, __shfl_xor(mc, 1, 64));
            mc = fmaxf(mc, __shfl_xor(mc, 2, 64));
            mc = fmaxf(mc, __shfl_xor(mc, 4, 64));
            mc = fmaxf(mc, __shfl_xor(mc, 8, 64));
            float mn = fmaxf(mprev[r], mc);
            float alpha = __expf(mprev[r] - mn);
            mprev[r] = mn;
            float rs = 0.f;
#pragma unroll
            for (int mt = 0; mt < 4; mt++) {
                float p = __expf(sacc[mt][r] - mn);
                sacc[mt][r] = p;
                rs += p;
            }
            rs += __shfl_xor(rs, 1, 64);
            rs += __shfl_xor(rs, 2, 64);
            rs += __shfl_xor(rs, 4, 64);
            rs += __shfl_xor(rs, 8, 64);
            lsum[r] = lsum[r] * alpha + rs;
#pragma unroll
            for (int ct = 0; ct < 8; ct++) oacc[ct][r] *= alpha;
            // P: C-layout -> LDS [n-local][m-local]
#pragma unroll
            for (int mt = 0; mt < 4; mt++)
                p_lds[w * 1152 + (quad * 4 + r) * 72 + mt * 16 + l15] = f2bf(sacc[mt][r]);
        }
        __syncthreads();   // conservative: ensure P visible before A-frag reads

        // O += P(16x64) . g_chunk(64x128)
#pragma unroll
        for (int kk = 0; kk < 2; kk++) {
            bf16x8 a = *(const bf16x8*)&p_lds[w * 1152 + l15 * 72 + kk * 32 + quad * 8];
#pragma unroll
            for (int ct = 0; ct < 8; ct++) {
                bf16x8 bb = *(const bf16x8*)&g_lds[(ct * 16 + l15) * 72 + kk * 32 + quad * 8];
                oacc[ct] = __builtin_amdgcn_mfma_f32_16x16x32_bf16(a, bb, oacc[ct], 0, 0, 0);
            }
        }
    }

    // epilogue: y[n][ci] = O / l   (row = quad*4+r, col = ct*16+l15)
#pragma unroll
    for (int r = 0; r < 4; r++) {
        float inv = 1.0f / lsum[r];
        int n = n0 + w * 16 + quad * 4 + r;
        float* yr = y + (size_t)(b * kN + n) * kCI;
#pragma unroll
        for (int ct = 0; ct < 8; ct++) yr[ct * 16 + l15] = oacc[ct][r] * inv;
    }
}

// ---------------------------------------------------------------------------
// transpose y [B][N][CI] fp32 -> yT [B][CI][N]
// ---------------------------------------------------------------------------
__global__ __launch_bounds__(256) void transpose_kernel(const float* __restrict__ in,
                                                        float* __restrict__ out) {
    __shared__ float tile[32][33];
    int b   = blockIdx.z;
    int n0  = blockIdx.x * 32;
    int ci0 = blockIdx.y * 32;
    int tx = threadIdx.x & 31, ty = threadIdx.x >> 5;
#pragma unroll
    for (int j = 0; j < 4; j++) {
        int row = ty + 8 * j;
        tile[row][tx] = in[(size_t)(b * kN + n0 + row) * kCI + ci0 + tx];
    }
    __syncthreads();
#pragma unroll
    for (int j = 0; j < 4; j++) {
        int row = ty + 8 * j;
        out[(size_t)(b * kCI + ci0 + row) * kN + n0 + tx] = tile[tx][row];
    }
}

// ---------------------------------------------------------------------------
// final: out = (Ww . yT + bw - mean)*scale + beta + v   (fp32)
// ---------------------------------------------------------------------------
__global__ __launch_bounds__(256) void final_kernel(const float* __restrict__ yT,
                                                    const float* __restrict__ Ww,
                                                    const float* __restrict__ bw,
                                                    const float* __restrict__ gamma,
                                                    const float* __restrict__ beta,
                                                    const float* __restrict__ mean,
                                                    const float* __restrict__ var,
                                                    const float* __restrict__ v,
                                                    float* __restrict__ out) {
    __shared__ float y_lds[kCI * 64];
    __shared__ float w_lds[64 * 129];
    int t  = threadIdx.x;
    int b  = blockIdx.y;
    int n0 = blockIdx.x * 64;
    int pxg = t & 15;
    int cog = t >> 4;

#pragma unroll
    for (int s = 0; s < 8; s++) {
        int idx = t + 256 * s;
        int p4 = (idx & 15) * 4, ci = idx >> 4;
        *(float4*)&y_lds[ci * 64 + p4] =
            *(const float4*)&yT[(size_t)(b * kCI + ci) * kN + n0 + p4];
    }

    for (int cpass = 0; cpass < 4; cpass++) {
        __syncthreads();
#pragma unroll
        for (int s = 0; s < 32; s++) {
            int idx = t + 256 * s;
            int ci = idx & 127, cop = idx >> 7;
            w_lds[cop * 129 + ci] = Ww[(cpass * 64 + cop) * kCI + ci];
        }
        __syncthreads();

        float acc[4][4];
#pragma unroll
        for (int jj = 0; jj < 4; jj++)
#pragma unroll
            for (int i = 0; i < 4; i++) acc[jj][i] = 0.0f;

#pragma unroll 4
        for (int ci = 0; ci < kCI; ci++) {
            float4 a = *(const float4*)&y_lds[ci * 64 + pxg * 4];
#pragma unroll
            for (int jj = 0; jj < 4; jj++) {
                float wv = w_lds[(cog * 4 + jj) * 129 + ci];
                acc[jj][0] += wv * a.x;
                acc[jj][1] += wv * a.y;
                acc[jj][2] += wv * a.z;
                acc[jj][3] += wv * a.w;
            }
        }

#pragma unroll
        for (int jj = 0; jj < 4; jj++) {
            int co = cpass * 64 + cog * 4 + jj;
            float sc = gamma[co] * rsqrtf(var[co] + kEPS);
            float bb = (bw[co] - mean[co]) * sc + beta[co];
            size_t base = (size_t)(b * kC + co) * kN + n0 + pxg * 4;
            float4 vv = *(const float4*)(v + base);
            float4 ov;
            ov.x = acc[jj][0] * sc + bb + vv.x;
            ov.y = acc[jj][1] * sc + bb + vv.y;
            ov.z = acc[jj][2] * sc + bb + vv.z;
            ov.w = acc[jj][3] * sc + bb + vv.w;
            *(float4*)(out + base) = ov;
        }
    }
}

// ---------------------------------------------------------------------------
extern "C" void kernel_launch(void* const* d_in, const int* in_sizes, int n_in,
                              void* d_out, int out_size, void* d_ws, size_t ws_size,
                              hipStream_t stream) {
    (void)in_sizes; (void)n_in; (void)out_size; (void)ws_size;
    const float* q     = (const float*)d_in[0];
    const float* k     = (const float*)d_in[1];
    const float* v     = (const float*)d_in[2];
    const float* Wg    = (const float*)d_in[3];
    const float* bg    = (const float*)d_in[4];
    const float* Wth   = (const float*)d_in[5];
    const float* bth   = (const float*)d_in[6];
    const float* Wph   = (const float*)d_in[7];
    const float* bph   = (const float*)d_in[8];
    const float* Ww    = (const float*)d_in[9];
    const float* bw    = (const float*)d_in[10];
    const float* gamma = (const float*)d_in[11];
    const float* beta  = (const float*)d_in[12];
    const float* mean  = (const float*)d_in[13];
    const float* var   = (const float*)d_in[14];
    float* out = (float*)d_out;

    float* ws = (float*)d_ws;
    // [0,2M) qp | [2M,4M) vp  -> later yv [0,4M)
    // [4M,6M) theta bf16 | [6M,6.5M) phi bf16 | [6.5M,7M) g bf16 -> later yT [4M,8M)
    float* qp    = ws;
    float* vp    = ws + 2097152;
    u16*   theta = (u16*)(ws + 4194304);
    u16*   phi   = (u16*)(ws + 6291456);
    u16*   gbuf  = (u16*)(ws + 6815744);
    float* yv    = ws;
    float* yT    = ws + 4194304;

    pool_kernel<<<dim3(8192), 256, 0, stream>>>(q, qp);
    pool_kernel<<<dim3(8192), 256, 0, stream>>>(v, vp);
    conv1x1_kernel<0><<<dim3(64, 8), 256, 0, stream>>>(k, Wth, bth, theta, kN);
    conv1x1_kernel<0><<<dim3(16, 8), 256, 0, stream>>>(qp, Wph, bph, phi, kM);
    conv1x1_kernel<1><<<dim3(16, 8), 256, 0, stream>>>(vp, Wg, bg, gbuf, kM);
    attn_kernel<<<dim3(64, 8), 256, 0, stream>>>(theta, phi, gbuf, yv);
    transpose_kernel<<<dim3(128, 4, 8), 256, 0, stream>>>(yv, yT);
    final_kernel<<<dim3(64, 8), 256, 0, stream>>>(yT, Ww, bw, gamma, beta, mean, var, v, out);
}

// Round 4
// 270.491 us; speedup vs baseline: 2.7480x; 1.7999x over previous
//
#include <hip/hip_runtime.h>
#include <cstddef>

typedef unsigned short u16;
typedef unsigned int u32;
typedef __attribute__((ext_vector_type(8))) __bf16 bf16x8;
typedef __attribute__((ext_vector_type(4))) float f32x4;

constexpr int kB = 8, kC = 256, kCI = 128, kN = 4096, kM = 1024;
constexpr float kEPS = 1e-5f;

__device__ __forceinline__ u16 f2bf(float f) {
    u32 u = __float_as_uint(f);
    u32 r = (u + 0x7fffu + ((u >> 16) & 1u)) >> 16;
    return (u16)r;
}

// ---------------------------------------------------------------------------
// prep: weights -> bf16; fold BN scale into Ww; bb = (bw-mean)*sc+beta
// grid 512 x 256
// ---------------------------------------------------------------------------
__global__ __launch_bounds__(256) void prep_kernel(const float* __restrict__ Wth,
                                                   const float* __restrict__ Wph,
                                                   const float* __restrict__ Wg,
                                                   const float* __restrict__ Ww,
                                                   const float* __restrict__ bw,
                                                   const float* __restrict__ gamma,
                                                   const float* __restrict__ beta,
                                                   const float* __restrict__ mean,
                                                   const float* __restrict__ var,
                                                   u16* __restrict__ Wthb,
                                                   u16* __restrict__ Wphb,
                                                   u16* __restrict__ Wgb,
                                                   u16* __restrict__ Wwsb,
                                                   float* __restrict__ bb) {
    int idx = blockIdx.x * 256 + threadIdx.x;
    if (idx < 32768) {
        Wthb[idx] = f2bf(Wth[idx]);
    } else if (idx < 65536) {
        int j = idx - 32768; Wphb[j] = f2bf(Wph[j]);
    } else if (idx < 98304) {
        int j = idx - 65536; Wgb[j] = f2bf(Wg[j]);
    } else {
        int j = idx - 98304;              // 0..32767, co = j>>7
        int co = j >> 7;
        float sc = gamma[co] * rsqrtf(var[co] + kEPS);
        Wwsb[j] = f2bf(Ww[j] * sc);
        if ((j & 127) == 0) bb[co] = (bw[co] - mean[co]) * sc + beta[co];
    }
}

// ---------------------------------------------------------------------------
// 2x2 avg pool: in fp32 [B*C][64][64] -> out fp32 [B*C][1024]
// ---------------------------------------------------------------------------
__global__ __launch_bounds__(256) void pool_kernel(const float* __restrict__ in,
                                                   float* __restrict__ out) {
    int idx = blockIdx.x * 256 + threadIdx.x;
    int m  = idx & (kM - 1);
    int bc = idx >> 10;
    int mh = m >> 5, mw = m & 31;
    const float* p = in + ((size_t)bc * 64 + 2 * mh) * 64 + 2 * mw;
    float2 a = *(const float2*)p;
    float2 b = *(const float2*)(p + 64);
    out[idx] = 0.25f * (a.x + a.y + b.x + b.y);
}

// ---------------------------------------------------------------------------
// MFMA producer conv1x1: x fp32 [b][256 c][Mn] . Wb bf16 [128 ci][256 c] + bias
// CMAJOR=0: out bf16 [b][n][ci]  (theta, phi)
// CMAJOR=1: out bf16 [b][ci][n]  (g)
// block 256 thr / 4 waves; tile 64 px x 128 ci; K-chunks of 64.
// x staged transposed+swizzled: elem (n,c) at lds[n*64 + ((c>>3)^(n&7))*8 + (c&7)]
// ---------------------------------------------------------------------------
template <int CMAJOR>
__global__ __launch_bounds__(256) void convp_kernel(const float* __restrict__ x,
                                                    const u16* __restrict__ Wb,
                                                    const float* __restrict__ bias,
                                                    u16* __restrict__ out, int Mn) {
    __shared__ __align__(16) u16 w_lds[128 * 72];   // [ci][c] stride 72
    __shared__ __align__(16) u16 x_lds[64 * 64];    // [n][c] swizzled, 128B rows
    int t = threadIdx.x, b = blockIdx.y, n0 = blockIdx.x * 64;
    int w = t >> 6, lane = t & 63, l15 = lane & 15, quad = lane >> 4;
    int xn = t & 63, cbb = (t >> 6) * 2;

    f32x4 acc[8];
#pragma unroll
    for (int i = 0; i < 8; i++) acc[i] = (f32x4){0.f, 0.f, 0.f, 0.f};

    for (int c0 = 0; c0 < kC; c0 += 64) {
        __syncthreads();
        // stage W chunk [128 ci][64 c]
#pragma unroll
        for (int i = 0; i < 4; i++) {
            int u = t + 256 * i;
            int ci = u >> 3, blk = u & 7;
            *(uint4*)&w_lds[ci * 72 + blk * 8] =
                *(const uint4*)&Wb[ci * kC + c0 + blk * 8];
        }
        // stage x chunk transposed: thread: n=xn, two 8-c blocks
#pragma unroll
        for (int cc = 0; cc < 2; cc++) {
            int cb = cbb + cc;
            float f[8];
#pragma unroll
            for (int j = 0; j < 8; j++)
                f[j] = x[(size_t)(b * kC + c0 + cb * 8 + j) * Mn + n0 + xn];
            uint4 pk;
            pk.x = (u32)f2bf(f[0]) | ((u32)f2bf(f[1]) << 16);
            pk.y = (u32)f2bf(f[2]) | ((u32)f2bf(f[3]) << 16);
            pk.z = (u32)f2bf(f[4]) | ((u32)f2bf(f[5]) << 16);
            pk.w = (u32)f2bf(f[6]) | ((u32)f2bf(f[7]) << 16);
            *(uint4*)&x_lds[xn * 64 + ((cb ^ (xn & 7)) * 8)] = pk;
        }
        __syncthreads();

#pragma unroll
        for (int ks = 0; ks < 2; ks++) {
            int px = w * 16 + l15;
            bf16x8 xf = *(const bf16x8*)&x_lds[px * 64 + (((ks * 4 + quad) ^ (px & 7)) * 8)];
#pragma unroll
            for (int ct = 0; ct < 8; ct++) {
                bf16x8 wf = *(const bf16x8*)&w_lds[(ct * 16 + l15) * 72 + ks * 32 + quad * 8];
                if (CMAJOR)
                    acc[ct] = __builtin_amdgcn_mfma_f32_16x16x32_bf16(xf, wf, acc[ct], 0, 0, 0);
                else
                    acc[ct] = __builtin_amdgcn_mfma_f32_16x16x32_bf16(wf, xf, acc[ct], 0, 0, 0);
            }
        }
    }

    if (CMAJOR == 0) {
        // D[ci][px]: lane: px = w*16+l15 fixed, rows ci = ct*16+quad*4+r
        int px = n0 + w * 16 + l15;
#pragma unroll
        for (int ct = 0; ct < 8; ct++) {
            int ci0 = ct * 16 + quad * 4;
            uint2 pk;
            pk.x = (u32)f2bf(acc[ct][0] + bias[ci0 + 0]) |
                   ((u32)f2bf(acc[ct][1] + bias[ci0 + 1]) << 16);
            pk.y = (u32)f2bf(acc[ct][2] + bias[ci0 + 2]) |
                   ((u32)f2bf(acc[ct][3] + bias[ci0 + 3]) << 16);
            *(uint2*)&out[(size_t)(b * Mn + px) * kCI + ci0] = pk;
        }
    } else {
        // D[px][ci]: lane: ci = ct*16+l15 fixed, rows px = quad*4+r
        int px = n0 + w * 16 + quad * 4;
#pragma unroll
        for (int ct = 0; ct < 8; ct++) {
            int ci = ct * 16 + l15;
            float bs = bias[ci];
            uint2 pk;
            pk.x = (u32)f2bf(acc[ct][0] + bs) | ((u32)f2bf(acc[ct][1] + bs) << 16);
            pk.y = (u32)f2bf(acc[ct][2] + bs) | ((u32)f2bf(acc[ct][3] + bs) << 16);
            *(uint2*)&out[(size_t)(b * kCI + ci) * Mn + px] = pk;
        }
    }
}

// ---------------------------------------------------------------------------
// Flash attention, bf16 MFMA. theta [B][N][CI], phi [B][M][CI], g [B][CI][M]
// y out: bf16 [B][N][CI]
// ---------------------------------------------------------------------------
__global__ __launch_bounds__(256) void attn_kernel(const u16* __restrict__ theta,
                                                   const u16* __restrict__ phi,
                                                   const u16* __restrict__ g,
                                                   u16* __restrict__ y) {
    __shared__ __align__(16) u16 th_lds[64 * 136];
    __shared__ __align__(16) u16 ph_lds[64 * 136];
    __shared__ __align__(16) u16 g_lds[128 * 72];
    __shared__ __align__(16) u16 p_lds[4 * 16 * 72];

    int t = threadIdx.x, b = blockIdx.y, n0 = blockIdx.x * 64;
    int w = t >> 6, lane = t & 63, l15 = lane & 15, quad = lane >> 4;

    const u16* thg = theta + (size_t)(b * kN + n0) * kCI;
#pragma unroll
    for (int it = 0; it < 4; it++) {
        int idx = t + 256 * it;
        int row = idx >> 4, col = (idx & 15) * 8;
        *(uint4*)&th_lds[row * 136 + col] = *(const uint4*)&thg[(size_t)row * kCI + col];
    }

    f32x4 oacc[8];
#pragma unroll
    for (int i = 0; i < 8; i++) oacc[i] = (f32x4){0.f, 0.f, 0.f, 0.f};
    float mprev[4], lsum[4];
#pragma unroll
    for (int r = 0; r < 4; r++) { mprev[r] = -1e30f; lsum[r] = 0.f; }

    const u16* phB = phi + (size_t)b * kM * kCI;
    const u16* gB  = g   + (size_t)b * kCI * kM;

    for (int c0 = 0; c0 < kM; c0 += 64) {
        __syncthreads();
#pragma unroll
        for (int it = 0; it < 4; it++) {
            int idx = t + 256 * it;
            int row = idx >> 4, col = (idx & 15) * 8;
            *(uint4*)&ph_lds[row * 136 + col] =
                *(const uint4*)&phB[(size_t)(c0 + row) * kCI + col];
        }
#pragma unroll
        for (int it = 0; it < 4; it++) {
            int idx = t + 256 * it;
            int row = idx >> 3, col = (idx & 7) * 8;
            *(uint4*)&g_lds[row * 72 + col] =
                *(const uint4*)&gB[(size_t)row * kM + c0 + col];
        }
        __syncthreads();

        f32x4 sacc[4];
#pragma unroll
        for (int mt = 0; mt < 4; mt++) sacc[mt] = (f32x4){0.f, 0.f, 0.f, 0.f};
#pragma unroll
        for (int kk = 0; kk < 4; kk++) {
            bf16x8 a = *(const bf16x8*)&th_lds[(w * 16 + l15) * 136 + kk * 32 + quad * 8];
#pragma unroll
            for (int mt = 0; mt < 4; mt++) {
                bf16x8 bb = *(const bf16x8*)&ph_lds[(mt * 16 + l15) * 136 + kk * 32 + quad * 8];
                sacc[mt] = __builtin_amdgcn_mfma_f32_16x16x32_bf16(a, bb, sacc[mt], 0, 0, 0);
            }
        }

#pragma unroll
        for (int r = 0; r < 4; r++) {
            float mc = fmaxf(fmaxf(sacc[0][r], sacc[1][r]), fmaxf(sacc[2][r], sacc[3][r]));
            mc = fmaxf(mc, __shfl_xor(mc, 1, 64));
            mc = fmaxf(mc, __shfl_xor(mc, 2, 64));
            mc = fmaxf(mc, __shfl_xor(mc, 4, 64));
            mc = fmaxf(mc, __shfl_xor(mc, 8, 64));
            float mn = fmaxf(mprev[r], mc);
            float alpha = __expf(mprev[r] - mn);
            mprev[r] = mn;
            float rs = 0.f;
#pragma unroll
            for (int mt = 0; mt < 4; mt++) {
                float p = __expf(sacc[mt][r] - mn);
                sacc[mt][r] = p;
                rs += p;
            }
            rs += __shfl_xor(rs, 1, 64);
            rs += __shfl_xor(rs, 2, 64);
            rs += __shfl_xor(rs, 4, 64);
            rs += __shfl_xor(rs, 8, 64);
            lsum[r] = lsum[r] * alpha + rs;
#pragma unroll
            for (int ct = 0; ct < 8; ct++) oacc[ct][r] *= alpha;
#pragma unroll
            for (int mt = 0; mt < 4; mt++)
                p_lds[w * 1152 + (quad * 4 + r) * 72 + mt * 16 + l15] = f2bf(sacc[mt][r]);
        }
        __syncthreads();

#pragma unroll
        for (int kk = 0; kk < 2; kk++) {
            bf16x8 a = *(const bf16x8*)&p_lds[w * 1152 + l15 * 72 + kk * 32 + quad * 8];
#pragma unroll
            for (int ct = 0; ct < 8; ct++) {
                bf16x8 bb = *(const bf16x8*)&g_lds[(ct * 16 + l15) * 72 + kk * 32 + quad * 8];
                oacc[ct] = __builtin_amdgcn_mfma_f32_16x16x32_bf16(a, bb, oacc[ct], 0, 0, 0);
            }
        }
    }

#pragma unroll
    for (int r = 0; r < 4; r++) {
        float inv = 1.0f / lsum[r];
        int n = n0 + w * 16 + quad * 4 + r;
        u16* yr = y + (size_t)(b * kN + n) * kCI;
#pragma unroll
        for (int ct = 0; ct < 8; ct++) yr[ct * 16 + l15] = f2bf(oacc[ct][r] * inv);
    }
}

// ---------------------------------------------------------------------------
// MFMA final conv: out[b][co][n] = Wws(bf16 [256][128]) . y(bf16 [b][n][128])
//                  + bb[co] + v[b][co][n]   (fp32 out)
// block 256 thr / 4 waves; tile 64 px; per wave: 16 co-tiles x 4 k-steps.
// A = y from LDS; B = Wws streamed from L2.
// ---------------------------------------------------------------------------
__global__ __launch_bounds__(256) void final_kernel(const u16* __restrict__ y,
                                                    const u16* __restrict__ Wws,
                                                    const float* __restrict__ bb,
                                                    const float* __restrict__ v,
                                                    float* __restrict__ out) {
    __shared__ __align__(16) u16 y_lds[64 * 136];
    int t = threadIdx.x, b = blockIdx.y, n0 = blockIdx.x * 64;
    int w = t >> 6, lane = t & 63, l15 = lane & 15, quad = lane >> 4;

#pragma unroll
    for (int i = 0; i < 4; i++) {
        int u = t + 256 * i;
        int row = u >> 4, blk = u & 15;
        *(uint4*)&y_lds[row * 136 + blk * 8] =
            *(const uint4*)&y[(size_t)(b * kN + n0 + row) * kCI + blk * 8];
    }
    __syncthreads();

    bf16x8 af[4];
#pragma unroll
    for (int ks = 0; ks < 4; ks++)
        af[ks] = *(const bf16x8*)&y_lds[(w * 16 + l15) * 136 + ks * 32 + quad * 8];

#pragma unroll
    for (int ct = 0; ct < 16; ct++) {
        f32x4 a = (f32x4){0.f, 0.f, 0.f, 0.f};
#pragma unroll
        for (int ks = 0; ks < 4; ks++) {
            bf16x8 bf = *(const bf16x8*)&Wws[(ct * 16 + l15) * kCI + ks * 32 + quad * 8];
            a = __builtin_amdgcn_mfma_f32_16x16x32_bf16(af[ks], bf, a, 0, 0, 0);
        }
        int co = ct * 16 + l15;
        float bbv = bb[co];
        size_t base = (size_t)(b * kC + co) * kN + n0 + w * 16 + quad * 4;
        float4 vv = *(const float4*)&v[base];
        float4 ov;
        ov.x = a[0] + bbv + vv.x;
        ov.y = a[1] + bbv + vv.y;
        ov.z = a[2] + bbv + vv.z;
        ov.w = a[3] + bbv + vv.w;
        *(float4*)&out[base] = ov;
    }
}

// ---------------------------------------------------------------------------
extern "C" void kernel_launch(void* const* d_in, const int* in_sizes, int n_in,
                              void* d_out, int out_size, void* d_ws, size_t ws_size,
                              hipStream_t stream) {
    (void)in_sizes; (void)n_in; (void)out_size; (void)ws_size;
    const float* q     = (const float*)d_in[0];
    const float* k     = (const float*)d_in[1];
    const float* v     = (const float*)d_in[2];
    const float* Wg    = (const float*)d_in[3];
    const float* bg    = (const float*)d_in[4];
    const float* Wth   = (const float*)d_in[5];
    const float* bth   = (const float*)d_in[6];
    const float* Wph   = (const float*)d_in[7];
    const float* bph   = (const float*)d_in[8];
    const float* Ww    = (const float*)d_in[9];
    const float* bw    = (const float*)d_in[10];
    const float* gamma = (const float*)d_in[11];
    const float* beta  = (const float*)d_in[12];
    const float* mean  = (const float*)d_in[13];
    const float* var   = (const float*)d_in[14];
    float* out = (float*)d_out;

    float* ws = (float*)d_ws;
    float* qp    = ws;                       // [0, 2M)
    float* vp    = ws + 2097152;             // [2M, 4M)
    u16*   theta = (u16*)(ws + 4194304);     // 4M u16 -> [4M, 6M)
    u16*   phi   = (u16*)(ws + 6291456);     // 1M u16 -> [6M, 6.5M)
    u16*   gbuf  = (u16*)(ws + 6815744);     // 1M u16 -> [6.5M, 7M)
    u16*   ybuf  = (u16*)(ws + 7340032);     // 4M u16 -> [7M, 9M)
    u16*   Wthb  = (u16*)(ws + 9437184);     // 32K u16
    u16*   Wphb  = Wthb + 32768;
    u16*   Wgb   = Wphb + 32768;
    u16*   Wwsb  = Wgb + 32768;
    float* bbuf  = (float*)(Wwsb + 32768);   // 256 f32

    prep_kernel<<<dim3(512), 256, 0, stream>>>(Wth, Wph, Wg, Ww, bw, gamma, beta,
                                               mean, var, Wthb, Wphb, Wgb, Wwsb, bbuf);
    pool_kernel<<<dim3(8192), 256, 0, stream>>>(q, qp);
    pool_kernel<<<dim3(8192), 256, 0, stream>>>(v, vp);
    convp_kernel<0><<<dim3(64, 8), 256, 0, stream>>>(k, Wthb, bth, theta, kN);
    convp_kernel<0><<<dim3(16, 8), 256, 0, stream>>>(qp, Wphb, bph, phi, kM);
    convp_kernel<1><<<dim3(16, 8), 256, 0, stream>>>(vp, Wgb, bg, gbuf, kM);
    attn_kernel<<<dim3(64, 8), 256, 0, stream>>>(theta, phi, gbuf, ybuf);
    final_kernel<<<dim3(64, 8), 256, 0, stream>>>(ybuf, Wwsb, bbuf, v, out);
}